// Round 7
// baseline (162.827 us; speedup 1.0000x reference)
//
#include <hip/hip_runtime.h>
#include <hip/hip_bf16.h>
#include <math.h>

#define NN 128
#define TRI 8256          // 128*129/2
#define BATCH 2048
#define M_L 10
#define KAPPA 0.276f

using half8  = __attribute__((ext_vector_type(8))) _Float16;  // MFMA A/B frag (4 VGPRs)
using half2v = __attribute__((ext_vector_type(2))) _Float16;
using f32x4  = __attribute__((ext_vector_type(4))) float;     // MFMA C/D frag

// ---------------------------------------------------------------------------
// fp64 Sturm sign count reading T directly from LDS ab_s (f32) with inline
// cvt. R15: replaces per-lane double a[10]/off2[9]/offa[9] register arrays
// (~56 VGPRs) -- the tail is 1 wave, and uniform-address ds_reads broadcast;
// unrolled loop lets the compiler hoist all 19 reads ahead of the fp64 chain.
// ---------------------------------------------------------------------------
__device__ inline int sturm_lds(const float* __restrict__ ab_s, double x) {
    double pm = 1.0;
    double p  = (double)ab_s[0] - x;
    int c = (p < 0.0);
    #pragma unroll
    for (int i = 1; i < M_L; i++) {
        double bb = (double)ab_s[10 + i - 1];
        double pn = ((double)ab_s[i] - x) * p - (bb * bb) * pm;
        c += ((pn < 0.0) != (p < 0.0));
        pm = p; p = pn;
    }
    return c;
}

// ---------------------------------------------------------------------------
// Kernel 1: per-batch fused Lanczos + eig tail.
// R15: matvec DIRECTLY from MFMA accumulators -- M is never materialized.
//   Lane (m,g) of wave w holds acc[bi][j][q] = M[16j+m][16*band+4g+q]
//   (band = w, w+4; mapping verified by the R7+ writeback). Per iteration:
//   zj = sum_q acc[bi][j][q] * y[16*band+4g+q]  (y: broadcast float4 reads),
//   reduce over g via shfl_xor(16,32), lanes<16 write part[w][16j+m],
//   wave-0 hub combines 4 slices. Deletes M writeback + Mr hoist (-32 VGPR)
//   + 2 barriers + M LDS residency. M stays fp32 (was fp16-rounded).
//   -> LDS = exactly 32768 (ys/part/ab_s alias the dead L buffer)
//   -> total regs ~ 35 arch + 64 AGPR <= 102  => 5 blocks/CU by BOTH limits
//   (R14 lesson: unified RF, 512 regs/slot; acc=64 AGPR is structural).
// R12/R13 tail: lane-split Sturm, branchless brackets, guard-free.
// R14 (kept): XOR-swizzled [128][128] L buffer, branchless stage scatter.
// ---------------------------------------------------------------------------
__global__ __launch_bounds__(256, 5) void lanczos_kernel(
    const float* __restrict__ net_out,
    const float* __restrict__ U1,
    const float* __restrict__ v_in,
    float* __restrict__ contrib)   // [BATCH]
{
    __shared__ __align__(16) _Float16 Msh[128 * 128];   // 32768 B exactly (L, swizzled)
    // aliases into Msh, valid only AFTER the post-GEMM barrier (L dead):
    float* ysf  = (float*)Msh;             // 128 f32  (bytes    0..511)
    float* part = (float*)(Msh + 256);     // 512 f32  (bytes  512..2559)
    float* ab_s = (float*)(Msh + 1280);    // 20  f32  (bytes 2560..2639)

    const int b = blockIdx.x;
    const int t = threadIdx.x;
    const int lane = t & 63;
    const int w = t >> 6;       // wave id 0..3

    // ---- issue wave-0 global loads EARLY (latency hides under staging) ----
    float2 vv = {0.f, 0.f}, uu = {0.f, 0.f};
    if (w == 0) {
        vv = *(const float2*)(v_in + (size_t)b * NN + 2 * lane);
        uu = *(const float2*)(U1 + (size_t)b * 128 + 2 * lane);
    }

    // ---- zero Msh (upper triangle must be 0; swizzle is zero-invariant) ----
    {
        unsigned long long* z = (unsigned long long*)Msh;
        #pragma unroll
        for (int k = t; k < 128 * 128 / 4; k += 256) z[k] = 0ULL;
    }
    __syncthreads();

    // ---- stage L: coalesced float4 reads of packed tril, swizzled scatter ----
    // r = floor((sqrt(8e+1)-1)/2) exact for e<=8255 (R13 proof).
    {
        const float4* src4 = (const float4*)(net_out + (size_t)b * TRI);
        for (int q = t; q < TRI / 4; q += 256) {
            float4 f = src4[q];
            const int e = 4 * q;
            float vals[4] = {f.x, f.y, f.z, f.w};
            #pragma unroll
            for (int i = 0; i < 4; i++) {
                int ei = e + i;
                int r = (int)((sqrtf((float)(8 * ei) + 1.0f) - 1.0f) * 0.5f);
                int c = ei - ((r * (r + 1)) >> 1);
                Msh[r * 128 + (c ^ ((r & 7) << 3))] = (_Float16)vals[i];
            }
        }
    }
    __syncthreads();

    // ---- GEMM: M = L * L^T into acc (NO writeback -- M lives in AGPRs) ----
    // row (16*j+m) & 7 == m & 7, so the swizzle term is ((m&7)<<3) throughout.
    const int m = lane & 15;
    const int g = lane >> 4;
    f32x4 acc[2][8];
    {
        const int sw = (m & 7) << 3;
        #pragma unroll
        for (int bi = 0; bi < 2; bi++)
            #pragma unroll
            for (int j = 0; j < 8; j++) acc[bi][j] = (f32x4){0.f, 0.f, 0.f, 0.f};
        const int band0 = w, band1 = w + 4;
        #pragma unroll
        for (int kc = 0; kc < 4; kc++) {
            const int col = (kc * 32 + g * 8) ^ sw;   // 8-half run stays contiguous
            half8 a0 = *(const half8*)&Msh[(16 * band0 + m) * 128 + col];
            half8 a1 = *(const half8*)&Msh[(16 * band1 + m) * 128 + col];
            #pragma unroll
            for (int j = 0; j < 8; j++) {
                half8 bfr = *(const half8*)&Msh[(16 * j + m) * 128 + col];
                acc[0][j] = __builtin_amdgcn_mfma_f32_16x16x32_f16(a0, bfr, acc[0][j], 0, 0, 0);
                acc[1][j] = __builtin_amdgcn_mfma_f32_16x16x32_f16(a1, bfr, acc[1][j], 0, 0, 0);
            }
        }
    }
    __syncthreads();   // ALL L reads complete -> ysf/part/ab_s may alias Msh

    // ---- wave-0 state init: x (2 elems/lane), gauge regs, first y ----
    float x0 = 0.f, x1 = 0.f, p0 = 0.f, p1 = 0.f, beta = 0.f;
    float u0c = 0.f, u1c = 0.f, u0m = 0.f, u1m = 0.f;
    const int l_ip = (lane + 8) & 63;                  // site (i+1, j)
    const int l_jp = (lane & 56) | ((lane + 1) & 7);   // site (i, j+1)
    const int l_im = (lane + 56) & 63;                 // site (i-1, j)
    const int l_jm = (lane & 56) | ((lane + 7) & 7);   // site (i, j-1)

    if (w == 0) {
        float s = vv.x * vv.x + vv.y * vv.y;
        #pragma unroll
        for (int o = 1; o < 64; o <<= 1) s += __shfl_xor(s, o, 64);
        float inv = 1.0f / sqrtf(s);
        x0 = vv.x * inv; x1 = vv.y * inv;
        u0c = uu.x; u1c = uu.y;
        u0m = __shfl(u0c, l_im, 64);   // u0 at (i-1, j)
        u1m = __shfl(u1c, l_jm, 64);   // u1 at (i, j-1)

        // first y = dd(x), stored as f32 (no fp16 rounding needed anymore)
        float a0 = __shfl(x0, l_ip, 64), a1 = __shfl(x1, l_ip, 64);
        float b0 = __shfl(x0, l_jp, 64), b1 = __shfl(x1, l_jp, 64);
        float c0 = __shfl(x0, l_im, 64), c1 = __shfl(x1, l_im, 64);
        float d0 = __shfl(x0, l_jm, 64), d1 = __shfl(x1, l_jm, 64);
        float y0 = x0 - KAPPA * (u0c * a0 + u1c * b0 + u0m * c0 + u1m * d0);
        float y1 = x1 - KAPPA * (u0c * a1 + u1c * b1 + u0m * c1 + u1m * d1);
        *(float2*)&ysf[2 * lane] = (float2){y0, y1};
    }
    __syncthreads();   // ysf ready

    // =================== loop: 2 barriers per iteration ===================
    for (int it = 0; it < M_L; it++) {
        // ---- all waves: matvec from AGPR-resident M ----
        {
            float4 yb0 = *(const float4*)&ysf[16 * w + 4 * g];        // band0 cols
            float4 yb1 = *(const float4*)&ysf[16 * (w + 4) + 4 * g];  // band1 cols
            float z[8];
            #pragma unroll
            for (int j = 0; j < 8; j++) {
                f32x4 A0 = acc[0][j], A1 = acc[1][j];
                float zj = A0[0] * yb0.x + A0[1] * yb0.y + A0[2] * yb0.z + A0[3] * yb0.w
                         + A1[0] * yb1.x + A1[1] * yb1.y + A1[2] * yb1.z + A1[3] * yb1.w;
                zj += __shfl_xor(zj, 16, 64);   // combine g0<->g1, g2<->g3
                zj += __shfl_xor(zj, 32, 64);   // combine pairs
                z[j] = zj;
            }
            if (lane < 16) {
                #pragma unroll
                for (int j = 0; j < 8; j++) part[w * 128 + 16 * j + lane] = z[j];
            }
        }
        __syncthreads();   // B1: part ready

        // ---- wave 0: combine 4 slices, reduce, update, dd, broadcast y ----
        if (w == 0) {
            float z0 = 0.f, z1 = 0.f;
            #pragma unroll
            for (int ww = 0; ww < 4; ww++) {
                float2 pw = *(const float2*)&part[ww * 128 + 2 * lane];
                z0 += pw.x; z1 += pw.y;
            }

            float s1 = z0 * x0 + z1 * x1;
            float s2 = z0 * z0 + z1 * z1;
            float s3 = z0 * p0 + z1 * p1;
            #pragma unroll
            for (int o = 1; o < 64; o <<= 1) {
                s1 += __shfl_xor(s1, o, 64);
                s2 += __shfl_xor(s2, o, 64);
                s3 += __shfl_xor(s3, o, 64);
            }
            float alpha = s1;
            float b2 = s2 - alpha * alpha - beta * (2.0f * s3 - beta);
            float bn = sqrtf(fmaxf(b2, 0.0f));
            float w0 = z0 - alpha * x0 - beta * p0;
            float w1 = z1 - alpha * x1 - beta * p1;
            float inv = 1.0f / (bn + 1e-30f);
            p0 = x0; p1 = x1;
            x0 = w0 * inv; x1 = w1 * inv;
            beta = bn;
            if (lane == 0) {
                ab_s[it]      = alpha;
                ab_s[10 + it] = bn;
            }

            // dd for next iteration
            float a0 = __shfl(x0, l_ip, 64), a1 = __shfl(x1, l_ip, 64);
            float b0 = __shfl(x0, l_jp, 64), b1 = __shfl(x1, l_jp, 64);
            float c0 = __shfl(x0, l_im, 64), c1 = __shfl(x1, l_im, 64);
            float d0 = __shfl(x0, l_jm, 64), d1 = __shfl(x1, l_jm, 64);
            float y0 = x0 - KAPPA * (u0c * a0 + u1c * b0 + u0m * c0 + u1m * d0);
            float y1 = x1 - KAPPA * (u0c * a1 + u1c * b1 + u0m * c1 + u1m * d1);
            *(float2*)&ysf[2 * lane] = (float2){y0, y1};
        }
        __syncthreads();   // B2: ysf ready for next matvec; also makes ab_s
                           //     visible to ALL waves after the last iter
    }

    // ============ eig tail: ONE wave (b&3), lane-split Sturm ============
    if (w != (b & 3)) return;   // no barriers below this point

    // Gershgorin bounds straight from LDS (broadcast reads, minimal regs)
    double glo = 1e300, ghi = -1e300;
    #pragma unroll
    for (int i = 0; i < M_L; i++) {
        double ai = (double)ab_s[i];
        double rr = 0.0;
        if (i > 0)        rr += fabs((double)ab_s[10 + i - 1]);
        if (i < M_L - 1)  rr += fabs((double)ab_s[10 + i]);
        glo = fmin(glo, ai - rr);
        ghi = fmax(ghi, ai + rr);
    }

    const int kk = lane & 31;
    const bool topHalf = (lane >= 32);

    // Phase 1: lanes 0-31 find lmax (K=10), lanes 32-63 find lmin (K=1);
    // 33-section x 4 rounds; branchless bracket update.
    const int K = topHalf ? 1 : M_L;
    double lo = glo, hi = ghi;
    for (int round = 0; round < 4; round++) {
        double wdt = (hi - lo) * (1.0 / 33.0);
        double x = lo + wdt * (double)(kk + 1);
        int cnt = sturm_lds(ab_s, x);
        unsigned long long m64 = __ballot(cnt >= K);
        unsigned mm = topHalf ? (unsigned)(m64 >> 32)
                              : (unsigned)(m64 & 0xffffffffu);
        int p = (mm == 0u) ? 32 : (__ffs(mm) - 1);
        double nlo = lo + wdt * (double)p;
        hi = (mm == 0u) ? hi : (lo + wdt * (double)(p + 1));
        lo = nlo;
    }
    double mid = 0.5 * (lo + hi);
    double lmax = __shfl(mid, 0, 64);
    double lmin = __shfl(mid, 32, 64);
    double maxabs = fmax(fabs(lmax), fabs(lmin));

    // Phase 2: window |lambda|min -- lanes 0-31 eval +s, lanes 32-63 eval -s;
    // combine via shfl_xor(32); 33-section x 4 rounds; branchless update.
    double wlo = 0.0, whi = maxabs;
    for (int round = 0; round < 4; round++) {
        double wdt = (whi - wlo) * (1.0 / 33.0);
        double s = wlo + wdt * (double)(kk + 1);
        double x = topHalf ? -s : s;
        int cnt = sturm_lds(ab_s, x);
        int o = __shfl_xor(cnt, 32, 64);
        int inwin = topHalf ? (o - cnt) : (cnt - o);
        unsigned long long m64 = __ballot(inwin >= 1);
        unsigned mm = (unsigned)(m64 & 0xffffffffu);   // halves mirror
        int p = (mm == 0u) ? 32 : (__ffs(mm) - 1);
        double nlo = wlo + wdt * (double)p;
        whi = (mm == 0u) ? whi : (wlo + wdt * (double)(p + 1));
        wlo = nlo;
    }
    double minabs = 0.5 * (wlo + whi);
    if (lane == 0) contrib[b] = (float)(maxabs * maxabs - minabs * minabs);
}

// ---------------------------------------------------------------------------
// Kernel 2: reduce 2048 contributions -> d_out[0] (mean)
// ---------------------------------------------------------------------------
__global__ __launch_bounds__(1024) void reduce_kernel(
    const float* __restrict__ contrib, float* __restrict__ out)
{
    __shared__ float red[16];
    int t = threadIdx.x;
    float s = contrib[t] + contrib[t + 1024];
    #pragma unroll
    for (int o = 32; o > 0; o >>= 1) s += __shfl_down(s, o, 64);
    if ((t & 63) == 0) red[t >> 6] = s;
    __syncthreads();
    if (t < 64) {
        float r = (t < 16) ? red[t] : 0.0f;
        #pragma unroll
        for (int o = 8; o > 0; o >>= 1) r += __shfl_down(r, o, 64);
        if (t == 0) out[0] = r / (float)BATCH;
    }
}

extern "C" void kernel_launch(void* const* d_in, const int* in_sizes, int n_in,
                              void* d_out, int out_size, void* d_ws, size_t ws_size,
                              hipStream_t stream) {
    const float* net_out = (const float*)d_in[0];
    const float* U1      = (const float*)d_in[1];
    const float* v       = (const float*)d_in[2];
    float* contrib = (float*)d_ws;   // BATCH floats

    lanczos_kernel<<<BATCH, 256, 0, stream>>>(net_out, U1, v, contrib);
    reduce_kernel<<<1, 1024, 0, stream>>>(contrib, (float*)d_out);
}